// Round 5
// baseline (11622.665 us; speedup 1.0000x reference)
//
#include <hip/hip_runtime.h>

// ---------------------------------------------------------------------------
// MambaEncoder on MI355X — round 5: tiled fp32 pipeline + FP32 OUTPUT (the
// round-2..4 failure was writing bf16 into an fp32 d_out). Inputs read via
// per-wave dtype sniff (handles bf16 or fp32 storage). Internal fp32.
// Dims: NL=8, DM=512, DI=1024, DS=16, DC=4, DR=32, B=8, L=800.
// ---------------------------------------------------------------------------

typedef unsigned short u16;
typedef unsigned long long u64;

__device__ __forceinline__ float b2f(u16 u) {
    return __uint_as_float(((unsigned)u) << 16);
}
__device__ __forceinline__ float ldw(const void* p, size_t i, int bf) {
    return bf ? b2f(((const u16*)p)[i]) : ((const float*)p)[i];
}
__device__ __forceinline__ float4 ldw4(const void* p, size_t i, int bf) {
    if (bf) {
        ushort4 v = *(const ushort4*)((const u16*)p + i);
        return make_float4(b2f(v.x), b2f(v.y), b2f(v.z), b2f(v.w));
    }
    return *(const float4*)((const float*)p + i);
}

// Per-wave dtype sniff of patch_w (values ~N(0,0.02), never zero):
// bf16 storage -> all 64 sampled u16s have sane exponents (cnt=64).
// fp32 storage -> only high halves do (cnt~36). Threshold 50.
__device__ __forceinline__ int detect_bf(const void* w) {
    const u16* p = (const u16*)w;
    unsigned e = (p[threadIdx.x & 63] >> 7) & 0xFFu;
    u64 m = __ballot((e >= 0x60u) && (e <= 0x7Fu));
    return __popcll(m) >= 50 ? 1 : 0;
}

// EPI: 0 none(no bias), 1 +bias, 2 +bias softplus, 3 +bias gelu(erf)
template<int EPI>
__device__ __forceinline__ float epi_act(float x) {
    if (EPI == 2) return x > 20.f ? x : log1pf(__expf(x));
    if (EPI == 3) return 0.5f * x * (1.f + erff(x * 0.7071067811865476f));
    return x;
}

// ---------------- GEMM: C = act((A[+A2]) * Bw (+bias)) ---------------------
// A fp32 (lda), Bw external KxN row-major (ldb) at element offset boff.
// BM=BN=64, BK=16, 256 thr, 4x4 microtile. All dims divide tiles exactly.
template<int EPI, bool ASUM>
__global__ __launch_bounds__(256) void gemm_f32(
    const float* __restrict__ A, const float* __restrict__ A2,
    const void* __restrict__ Bw, size_t boff,
    const void* __restrict__ bias, size_t soff,
    float* __restrict__ C, int N, int K, int lda, int ldb, int ldc,
    const void* __restrict__ sniff)
{
    const int bf = detect_bf(sniff);
    __shared__ float As[16][68];
    __shared__ float Bs[16][68];
    const int tid = threadIdx.x;
    const int bm = blockIdx.y * 64;
    const int bn = blockIdx.x * 64;
    const int arow = tid >> 2, acol = (tid & 3) << 2;
    const int brow = tid >> 4, bcol = (tid & 15) << 2;
    const int ty = tid >> 4, tx = tid & 15;
    float acc[4][4] = {};

    const float* aptr  = A + (size_t)(bm + arow) * lda + acol;
    const float* aptr2 = ASUM ? (A2 + (size_t)(bm + arow) * lda + acol) : nullptr;
    const size_t bidx0 = boff + (size_t)brow * ldb + bn + bcol;

    for (int k0 = 0; k0 < K; k0 += 16) {
        float4 av = *(const float4*)(aptr + k0);
        if (ASUM) {
            float4 a2 = *(const float4*)(aptr2 + k0);
            av.x += a2.x; av.y += a2.y; av.z += a2.z; av.w += a2.w;
        }
        float4 bv = ldw4(Bw, bidx0 + (size_t)k0 * ldb, bf);
        As[acol + 0][arow] = av.x;
        As[acol + 1][arow] = av.y;
        As[acol + 2][arow] = av.z;
        As[acol + 3][arow] = av.w;
        Bs[brow][bcol + 0] = bv.x;
        Bs[brow][bcol + 1] = bv.y;
        Bs[brow][bcol + 2] = bv.z;
        Bs[brow][bcol + 3] = bv.w;
        __syncthreads();
        #pragma unroll
        for (int kk = 0; kk < 16; kk++) {
            float4 a4 = *(const float4*)&As[kk][ty << 2];
            float4 b4 = *(const float4*)&Bs[kk][tx << 2];
            float ar[4] = {a4.x, a4.y, a4.z, a4.w};
            float br[4] = {b4.x, b4.y, b4.z, b4.w};
            #pragma unroll
            for (int i = 0; i < 4; i++)
                #pragma unroll
                for (int j = 0; j < 4; j++)
                    acc[i][j] = fmaf(ar[i], br[j], acc[i][j]);
        }
        __syncthreads();
    }

    float bv4[4] = {0.f, 0.f, 0.f, 0.f};
    if (EPI >= 1) {
        float4 bb = ldw4(bias, soff + (size_t)(bn + (tx << 2)), bf);
        bv4[0] = bb.x; bv4[1] = bb.y; bv4[2] = bb.z; bv4[3] = bb.w;
    }
    #pragma unroll
    for (int i = 0; i < 4; i++) {
        float4 o;
        o.x = epi_act<EPI>(acc[i][0] + bv4[0]);
        o.y = epi_act<EPI>(acc[i][1] + bv4[1]);
        o.z = epi_act<EPI>(acc[i][2] + bv4[2]);
        o.w = epi_act<EPI>(acc[i][3] + bv4[3]);
        *(float4*)(C + (size_t)(bm + (ty << 2) + i) * ldc + bn + (tx << 2)) = o;
    }
}

// ---------------- patch gather (im2col), one chunk -------------------------
// token = f*100+h*10+w; feature = (p1*16+p2)*4+pf
__global__ __launch_bounds__(256) void im2col_patch(
    const void* __restrict__ x, size_t x0, float* __restrict__ Pa,
    const void* __restrict__ sniff)
{
    const int bf = detect_bf(sniff);
    int idx = blockIdx.x * 256 + threadIdx.x;
    int p2 = idx & 15; int r = idx >> 4;
    int p1 = r & 15;  r >>= 4;
    int w = r % 10;   r /= 10;
    int h = r % 10;   r /= 10;
    int f = r & 7;    int b = r >> 3;            // b local in [0, bc)
    int token = f * 100 + h * 10 + w;
    size_t xb = x0 + ((size_t)(b * 32 + f * 4) * 160 + h * 16 + p1) * 160
                   + (w * 16 + p2);
    float* dst = Pa + (size_t)(b * 800 + token) * 1024 + ((p1 * 16 + p2) << 2);
    dst[0] = ldw(x, xb,         bf);
    dst[1] = ldw(x, xb + 25600, bf);   // pf stride = 160*160
    dst[2] = ldw(x, xb + 51200, bf);
    dst[3] = ldw(x, xb + 76800, bf);
}

// ---------------- dual depthwise conv + SiLU -------------------------------
// fwd: silu(bF + sum_k wF[k]*xm[t-3+k]); bwd(orig coords): wB[k]*xm[t+3-k]
__global__ __launch_bounds__(256) void conv_dual(
    const float* __restrict__ xm,
    const void* __restrict__ cwF, size_t wFo,
    const void* __restrict__ cbF, size_t bFo,
    const void* __restrict__ cwB, size_t wBo,
    const void* __restrict__ cbB, size_t bBo,
    float* __restrict__ xcf, float* __restrict__ xcb,
    const void* __restrict__ sniff)
{
    const int bf = detect_bf(sniff);
    int idx = blockIdx.x * 256 + threadIdx.x;
    int d = idx & 1023;
    int bt = idx >> 10;
    int t = bt % 800, b = bt / 800;
    const float* base = xm + (size_t)b * 800 * 2048 + d;
    float v[7];
    #pragma unroll
    for (int j = 0; j < 7; j++) {
        int tt = t + j - 3;
        v[j] = (tt >= 0 && tt < 800) ? base[(size_t)tt * 2048] : 0.f;
    }
    float4 wf = ldw4(cwF, wFo + (size_t)d * 4, bf);
    float4 wb = ldw4(cwB, wBo + (size_t)d * 4, bf);
    float f = ldw(cbF, bFo + d, bf) + wf.x * v[0] + wf.y * v[1]
                                    + wf.z * v[2] + wf.w * v[3];
    float g = ldw(cbB, bBo + d, bf) + wb.x * v[6] + wb.y * v[5]
                                    + wb.z * v[4] + wb.w * v[3];
    xcf[(size_t)bt * 1024 + d] = f / (1.f + __expf(-f));
    xcb[(size_t)bt * 1024 + d] = g / (1.f + __expf(-g));
}

// ---------------- selective scan, both dirs, in-place y over u -------------
// block 256 = 16 d-groups x 16 n; grid = (64, bc, 2); dir=1 walks t backward.
__global__ __launch_bounds__(256) void ssm_scan(
    const float* uF, const float* dtF, const float* __restrict__ pF,
    const float* uB, const float* dtB, const float* __restrict__ pB,
    const void* __restrict__ AlF, const void* __restrict__ AlB, size_t ao,
    const void* __restrict__ DF,  const void* __restrict__ DB,  size_t dofs,
    const float* __restrict__ z,
    float* yF, float* yB, const void* __restrict__ sniff)
{
    const int bf = detect_bf(sniff);
    const int dir = blockIdx.z;
    const int b = blockIdx.y;
    const int tid = threadIdx.x;
    const int dl = tid >> 4, n = tid & 15;
    const int d = blockIdx.x * 16 + dl;
    const float* u  = dir ? uB  : uF;
    const float* dt = dir ? dtB : dtF;
    const float* pr = dir ? pB  : pF;
    const void* Al  = dir ? AlB : AlF;
    const void* Dp  = dir ? DB  : DF;
    float* y        = dir ? yB  : yF;
    const float Ac = -__expf(ldw(Al, ao + (size_t)d * 16 + n, bf));
    const float Dv = ldw(Dp, dofs + d, bf);
    float h = 0.f;
    const size_t rb = (size_t)b * 800;
    for (int s = 0; s < 800; s++) {
        int t = dir ? 799 - s : s;
        size_t row = rb + t;
        float dtv = dt[row * 1024 + d];
        float uv  = u[row * 1024 + d];
        float Bv  = pr[row * 64 + 32 + n];
        float Cv  = pr[row * 64 + 48 + n];
        h = __expf(dtv * Ac) * h + (dtv * uv) * Bv;
        float c = h * Cv;
        c += __shfl_xor(c, 8, 16);
        c += __shfl_xor(c, 4, 16);
        c += __shfl_xor(c, 2, 16);
        c += __shfl_xor(c, 1, 16);
        if (n == 0) {
            float zv = z[row * 2048 + d];
            y[row * 1024 + d] = (c + uv * Dv) * (zv / (1.f + __expf(-zv)));
        }
    }
}

// ---------------- LayerNorm(Y)*g+b + XT -> XT (optional FP32 emit) ---------
// one wave per token; block = 4 tokens; grid = Mc/4
__global__ __launch_bounds__(256) void ln_residual(
    const float* __restrict__ Y, const void* __restrict__ g, size_t go,
    const void* __restrict__ bb, size_t bo,
    float* __restrict__ XT, float* __restrict__ out,
    const void* __restrict__ sniff)
{
    const int bf = detect_bf(sniff);
    int wv = threadIdx.x >> 6, lane = threadIdx.x & 63;
    int token = blockIdx.x * 4 + wv;
    const float* y = Y + (size_t)token * 512;
    float v[8], s = 0.f, s2 = 0.f;
    #pragma unroll
    for (int j = 0; j < 8; j++) {
        v[j] = y[lane + j * 64];
        s += v[j]; s2 += v[j] * v[j];
    }
    #pragma unroll
    for (int off = 32; off >= 1; off >>= 1) {
        s  += __shfl_xor(s,  off, 64);
        s2 += __shfl_xor(s2, off, 64);
    }
    float mean = s * (1.f / 512.f);
    float var  = s2 * (1.f / 512.f) - mean * mean;
    float rs = rsqrtf(var + 1e-5f);
    float* xt = XT + (size_t)token * 512;
    #pragma unroll
    for (int j = 0; j < 8; j++) {
        int c = lane + j * 64;
        float val = (v[j] - mean) * rs * ldw(g, go + c, bf)
                  + ldw(bb, bo + c, bf) + xt[c];
        xt[c] = val;
        if (out) out[(size_t)token * 512 + c] = val;   // FP32 output
    }
}

// ---------------------------------------------------------------------------
extern "C" void kernel_launch(void* const* d_in, const int* in_sizes, int n_in,
                              void* d_out, int out_size, void* d_ws, size_t ws_size,
                              hipStream_t stream)
{
    (void)in_sizes; (void)n_in; (void)out_size;
    const void* X      = d_in[0];
    const void* patchW = d_in[1];
    const void* patchB = d_in[2];
    const void* inW    = d_in[3];
    const void* convW  = d_in[4];
    const void* convBi = d_in[5];
    const void* xprojW = d_in[6];
    const void* dtW    = d_in[7];
    const void* dtBias = d_in[8];
    const void* Alog   = d_in[9];
    const void* Dsk    = d_in[10];
    const void* convWb = d_in[11];
    const void* convBb = d_in[12];
    const void* xprojWb= d_in[13];
    const void* dtWb   = d_in[14];
    const void* dtBiasb= d_in[15];
    const void* Alogb  = d_in[16];
    const void* Dskb   = d_in[17];
    const void* outW   = d_in[18];
    const void* ln1g   = d_in[19];
    const void* ln1b   = d_in[20];
    const void* fc1W   = d_in[21];
    const void* fc1B   = d_in[22];
    const void* fc2W   = d_in[23];
    const void* fc2B   = d_in[24];
    const void* ln2g   = d_in[25];
    const void* ln2b   = d_in[26];
    const void* SN     = patchW;            // dtype sniff target

    // chunking: per-chunk need = Mc * 6784 floats
    int nc = 1;
    if ((size_t)6400 * 6784 * 4 > ws_size) nc = 2;
    if ((size_t)3200 * 6784 * 4 > ws_size) nc = 4;
    if ((size_t)1600 * 6784 * 4 > ws_size) nc = 8;
    const int bc = 8 / nc;
    const int Mc = bc * 800;
    const int GY = Mc / 64;

    float* ws   = (float*)d_ws;
    float* XT   = ws;                           // Mc*512  (residual stream)
    float* XZ   = XT  + (size_t)Mc * 512;       // Mc*2048 (xm | z)
    float* XCF  = XZ  + (size_t)Mc * 2048;      // Mc*1024 (patch-A, convF, yF)
    float* XCB  = XCF + (size_t)Mc * 1024;      // Mc*1024 (convB, yB)
    float* PRF  = XCB + (size_t)Mc * 1024;      // Mc*64
    float* PRB  = PRF + (size_t)Mc * 64;        // Mc*64
    float* DTF  = PRB + (size_t)Mc * 64;        // Mc*1024
    float* DTB  = DTF + (size_t)Mc * 1024;      // Mc*1024
    float* PATCH = XCF;
    float* M1   = XZ;                           // MLP hidden (XZ dead post-scan)
    float* YO   = XZ + (size_t)Mc * 1024;       // out_proj out / MLP out
    float* M2   = YO;

    for (int c = 0; c < nc; c++) {
        const size_t x0 = (size_t)c * bc * 819200;      // 32*160*160 per batch

        im2col_patch<<<Mc, 256, 0, stream>>>(X, x0, PATCH, SN);
        gemm_f32<1, false><<<dim3(8, GY), 256, 0, stream>>>(
            PATCH, nullptr, patchW, 0, patchB, 0, XT,
            512, 1024, 1024, 512, 512, SN);

        for (int l = 0; l < 8; l++) {
            // in_proj: (Mc x 512) @ (512 x 2048) -> XZ (xm | z)
            gemm_f32<0, false><<<dim3(32, GY), 256, 0, stream>>>(
                XT, nullptr, inW, (size_t)l * 1048576, nullptr, 0, XZ,
                2048, 512, 512, 2048, 2048, SN);
            // depthwise conv both dirs + SiLU
            conv_dual<<<Mc * 4, 256, 0, stream>>>(
                XZ, convW, (size_t)l * 4096, convBi, (size_t)l * 1024,
                convWb, (size_t)l * 4096, convBb, (size_t)l * 1024,
                XCF, XCB, SN);
            // x-proj both dirs: (Mc x 1024) @ (1024 x 64)
            gemm_f32<0, false><<<dim3(1, GY), 256, 0, stream>>>(
                XCF, nullptr, xprojW, (size_t)l * 65536, nullptr, 0, PRF,
                64, 1024, 1024, 64, 64, SN);
            gemm_f32<0, false><<<dim3(1, GY), 256, 0, stream>>>(
                XCB, nullptr, xprojWb, (size_t)l * 65536, nullptr, 0, PRB,
                64, 1024, 1024, 64, 64, SN);
            // dt: softplus((Mc x 32) @ (32 x 1024) + bias)
            gemm_f32<2, false><<<dim3(16, GY), 256, 0, stream>>>(
                PRF, nullptr, dtW, (size_t)l * 32768, dtBias, (size_t)l * 1024,
                DTF, 1024, 32, 64, 1024, 1024, SN);
            gemm_f32<2, false><<<dim3(16, GY), 256, 0, stream>>>(
                PRB, nullptr, dtWb, (size_t)l * 32768, dtBiasb, (size_t)l * 1024,
                DTB, 1024, 32, 64, 1024, 1024, SN);
            // selective scan both dirs (in-place y over u)
            ssm_scan<<<dim3(64, bc, 2), 256, 0, stream>>>(
                XCF, DTF, PRF, XCB, DTB, PRB,
                Alog, Alogb, (size_t)l * 16384,
                Dsk, Dskb, (size_t)l * 1024,
                XZ + 1024, XCF, XCB, SN);
            // out_proj with fused (yF + yB): (Mc x 1024) @ (1024 x 512)
            gemm_f32<0, true><<<dim3(8, GY), 256, 0, stream>>>(
                XCF, XCB, outW, (size_t)l * 524288, nullptr, 0, YO,
                512, 1024, 1024, 512, 512, SN);
            ln_residual<<<Mc / 4, 256, 0, stream>>>(
                YO, ln1g, (size_t)l * 512, ln1b, (size_t)l * 512, XT,
                nullptr, SN);
            // MLP
            gemm_f32<3, false><<<dim3(16, GY), 256, 0, stream>>>(
                XT, nullptr, fc1W, (size_t)l * 524288, fc1B, (size_t)l * 1024,
                M1, 1024, 512, 512, 1024, 1024, SN);
            gemm_f32<1, false><<<dim3(8, GY), 256, 0, stream>>>(
                M1, nullptr, fc2W, (size_t)l * 524288, fc2B, (size_t)l * 512,
                M2, 512, 1024, 1024, 512, 512, SN);
            ln_residual<<<Mc / 4, 256, 0, stream>>>(
                M2, ln2g, (size_t)l * 512, ln2b, (size_t)l * 512, XT,
                (float*)d_out + (size_t)l * 3276800 + (size_t)c * Mc * 512, SN);
        }
    }
}

// Round 6
// 7926.583 us; speedup vs baseline: 1.4663x; 1.4663x over previous
//
#include <hip/hip_runtime.h>

// ---------------------------------------------------------------------------
// MambaEncoder on MI355X — round 6: scan MLP fix (unroll-by-8 prefetch) +
// fused dual-direction small GEMMs. fp32 internal, fp32 output.
// Dims: NL=8, DM=512, DI=1024, DS=16, DC=4, DR=32, B=8, L=800.
// ---------------------------------------------------------------------------

typedef unsigned short u16;
typedef unsigned long long u64;

__device__ __forceinline__ float b2f(u16 u) {
    return __uint_as_float(((unsigned)u) << 16);
}
__device__ __forceinline__ float ldw(const void* p, size_t i, int bf) {
    return bf ? b2f(((const u16*)p)[i]) : ((const float*)p)[i];
}
__device__ __forceinline__ float4 ldw4(const void* p, size_t i, int bf) {
    if (bf) {
        ushort4 v = *(const ushort4*)((const u16*)p + i);
        return make_float4(b2f(v.x), b2f(v.y), b2f(v.z), b2f(v.w));
    }
    return *(const float4*)((const float*)p + i);
}

// Per-wave dtype sniff of patch_w (values ~N(0,0.02)): bf16 storage -> all 64
// sampled u16s have sane exponents; fp32 storage -> only high halves (~36/64).
__device__ __forceinline__ int detect_bf(const void* w) {
    const u16* p = (const u16*)w;
    unsigned e = (p[threadIdx.x & 63] >> 7) & 0xFFu;
    u64 m = __ballot((e >= 0x60u) && (e <= 0x7Fu));
    return __popcll(m) >= 50 ? 1 : 0;
}

// EPI: 0 none(no bias), 1 +bias, 2 +bias softplus, 3 +bias gelu(erf)
template<int EPI>
__device__ __forceinline__ float epi_act(float x) {
    if (EPI == 2) return x > 20.f ? x : log1pf(__expf(x));
    if (EPI == 3) return 0.5f * x * (1.f + erff(x * 0.7071067811865476f));
    return x;
}

// ---------------- shared GEMM body: C = act((A[+A2]) * Bw (+bias)) ---------
// A fp32 (lda), Bw external KxN row-major (ldb) at element offset boff.
// BM=BN=64, BK=16, 256 thr, 4x4 microtile. All dims divide tiles exactly.
template<int EPI, bool ASUM>
__device__ __forceinline__ void gemm_body(
    const float* __restrict__ A, const float* __restrict__ A2,
    const void* __restrict__ Bw, size_t boff,
    const void* __restrict__ bias, size_t soff,
    float* __restrict__ C, int N, int K, int lda, int ldb, int ldc, int bf)
{
    __shared__ float As[16][68];
    __shared__ float Bs[16][68];
    const int tid = threadIdx.x;
    const int bm = blockIdx.y * 64;
    const int bn = blockIdx.x * 64;
    const int arow = tid >> 2, acol = (tid & 3) << 2;
    const int brow = tid >> 4, bcol = (tid & 15) << 2;
    const int ty = tid >> 4, tx = tid & 15;
    float acc[4][4] = {};

    const float* aptr  = A + (size_t)(bm + arow) * lda + acol;
    const float* aptr2 = ASUM ? (A2 + (size_t)(bm + arow) * lda + acol) : nullptr;
    const size_t bidx0 = boff + (size_t)brow * ldb + bn + bcol;

    for (int k0 = 0; k0 < K; k0 += 16) {
        float4 av = *(const float4*)(aptr + k0);
        if (ASUM) {
            float4 a2 = *(const float4*)(aptr2 + k0);
            av.x += a2.x; av.y += a2.y; av.z += a2.z; av.w += a2.w;
        }
        float4 bv = ldw4(Bw, bidx0 + (size_t)k0 * ldb, bf);
        As[acol + 0][arow] = av.x;
        As[acol + 1][arow] = av.y;
        As[acol + 2][arow] = av.z;
        As[acol + 3][arow] = av.w;
        Bs[brow][bcol + 0] = bv.x;
        Bs[brow][bcol + 1] = bv.y;
        Bs[brow][bcol + 2] = bv.z;
        Bs[brow][bcol + 3] = bv.w;
        __syncthreads();
        #pragma unroll
        for (int kk = 0; kk < 16; kk++) {
            float4 a4 = *(const float4*)&As[kk][ty << 2];
            float4 b4 = *(const float4*)&Bs[kk][tx << 2];
            float ar[4] = {a4.x, a4.y, a4.z, a4.w};
            float br[4] = {b4.x, b4.y, b4.z, b4.w};
            #pragma unroll
            for (int i = 0; i < 4; i++)
                #pragma unroll
                for (int j = 0; j < 4; j++)
                    acc[i][j] = fmaf(ar[i], br[j], acc[i][j]);
        }
        __syncthreads();
    }

    float bv4[4] = {0.f, 0.f, 0.f, 0.f};
    if (EPI >= 1) {
        float4 bb = ldw4(bias, soff + (size_t)(bn + (tx << 2)), bf);
        bv4[0] = bb.x; bv4[1] = bb.y; bv4[2] = bb.z; bv4[3] = bb.w;
    }
    #pragma unroll
    for (int i = 0; i < 4; i++) {
        float4 o;
        o.x = epi_act<EPI>(acc[i][0] + bv4[0]);
        o.y = epi_act<EPI>(acc[i][1] + bv4[1]);
        o.z = epi_act<EPI>(acc[i][2] + bv4[2]);
        o.w = epi_act<EPI>(acc[i][3] + bv4[3]);
        *(float4*)(C + (size_t)(bm + (ty << 2) + i) * ldc + bn + (tx << 2)) = o;
    }
}

template<int EPI, bool ASUM>
__global__ __launch_bounds__(256) void gemm_f32(
    const float* __restrict__ A, const float* __restrict__ A2,
    const void* __restrict__ Bw, size_t boff,
    const void* __restrict__ bias, size_t soff,
    float* __restrict__ C, int N, int K, int lda, int ldb, int ldc,
    const void* __restrict__ sniff)
{
    const int bf = detect_bf(sniff);
    gemm_body<EPI, ASUM>(A, A2, Bw, boff, bias, soff, C, N, K, lda, ldb, ldc, bf);
}

// Dual-direction GEMM: blockIdx.z selects (A,Bw,bias,C) set. Same body.
template<int EPI>
__global__ __launch_bounds__(256) void gemm_dual(
    const float* __restrict__ A0, const float* __restrict__ A1,
    const void* __restrict__ Bw0, size_t boff0,
    const void* __restrict__ Bw1, size_t boff1,
    const void* __restrict__ bias0, size_t sof0,
    const void* __restrict__ bias1, size_t sof1,
    float* __restrict__ C0, float* __restrict__ C1,
    int N, int K, int lda, int ldb, int ldc,
    const void* __restrict__ sniff)
{
    const int bf = detect_bf(sniff);
    if (blockIdx.z == 0)
        gemm_body<EPI, false>(A0, nullptr, Bw0, boff0, bias0, sof0, C0,
                              N, K, lda, ldb, ldc, bf);
    else
        gemm_body<EPI, false>(A1, nullptr, Bw1, boff1, bias1, sof1, C1,
                              N, K, lda, ldb, ldc, bf);
}

// ---------------- patch gather (im2col), one chunk -------------------------
__global__ __launch_bounds__(256) void im2col_patch(
    const void* __restrict__ x, size_t x0, float* __restrict__ Pa,
    const void* __restrict__ sniff)
{
    const int bf = detect_bf(sniff);
    int idx = blockIdx.x * 256 + threadIdx.x;
    int p2 = idx & 15; int r = idx >> 4;
    int p1 = r & 15;  r >>= 4;
    int w = r % 10;   r /= 10;
    int h = r % 10;   r /= 10;
    int f = r & 7;    int b = r >> 3;
    int token = f * 100 + h * 10 + w;
    size_t xb = x0 + ((size_t)(b * 32 + f * 4) * 160 + h * 16 + p1) * 160
                   + (w * 16 + p2);
    float* dst = Pa + (size_t)(b * 800 + token) * 1024 + ((p1 * 16 + p2) << 2);
    dst[0] = ldw(x, xb,         bf);
    dst[1] = ldw(x, xb + 25600, bf);
    dst[2] = ldw(x, xb + 51200, bf);
    dst[3] = ldw(x, xb + 76800, bf);
}

// ---------------- dual depthwise conv + SiLU -------------------------------
__global__ __launch_bounds__(256) void conv_dual(
    const float* __restrict__ xm,
    const void* __restrict__ cwF, size_t wFo,
    const void* __restrict__ cbF, size_t bFo,
    const void* __restrict__ cwB, size_t wBo,
    const void* __restrict__ cbB, size_t bBo,
    float* __restrict__ xcf, float* __restrict__ xcb,
    const void* __restrict__ sniff)
{
    const int bf = detect_bf(sniff);
    int idx = blockIdx.x * 256 + threadIdx.x;
    int d = idx & 1023;
    int bt = idx >> 10;
    int t = bt % 800, b = bt / 800;
    const float* base = xm + (size_t)b * 800 * 2048 + d;
    float v[7];
    #pragma unroll
    for (int j = 0; j < 7; j++) {
        int tt = t + j - 3;
        v[j] = (tt >= 0 && tt < 800) ? base[(size_t)tt * 2048] : 0.f;
    }
    float4 wf = ldw4(cwF, wFo + (size_t)d * 4, bf);
    float4 wb = ldw4(cwB, wBo + (size_t)d * 4, bf);
    float f = ldw(cbF, bFo + d, bf) + wf.x * v[0] + wf.y * v[1]
                                    + wf.z * v[2] + wf.w * v[3];
    float g = ldw(cbB, bBo + d, bf) + wb.x * v[6] + wb.y * v[5]
                                    + wb.z * v[4] + wb.w * v[3];
    xcf[(size_t)bt * 1024 + d] = f / (1.f + __expf(-f));
    xcb[(size_t)bt * 1024 + d] = g / (1.f + __expf(-g));
}

// ---------------- selective scan, unroll-by-8 prefetch ---------------------
// block 256 = 16 d-groups x 16 n; grid = (64, bc, 2); dir=1 walks t backward.
// All loads for 8 t-steps issued before the serial recurrence consumes them
// (40 in-flight loads/thread -> BW-bound instead of latency-bound).
// y written in place over u (load of each row precedes its store).
__global__ __launch_bounds__(256) void ssm_scan(
    const float* uF, const float* dtF, const float* __restrict__ pF,
    const float* uB, const float* dtB, const float* __restrict__ pB,
    const void* __restrict__ AlF, const void* __restrict__ AlB, size_t ao,
    const void* __restrict__ DF,  const void* __restrict__ DB,  size_t dofs,
    const float* __restrict__ z,
    float* yF, float* yB, const void* __restrict__ sniff)
{
    const int bf = detect_bf(sniff);
    const int dir = blockIdx.z;
    const int b = blockIdx.y;
    const int tid = threadIdx.x;
    const int dl = tid >> 4, n = tid & 15;
    const int d = blockIdx.x * 16 + dl;
    const float* u  = dir ? uB  : uF;
    const float* dt = dir ? dtB : dtF;
    const float* pr = dir ? pB  : pF;
    const void* Al  = dir ? AlB : AlF;
    const void* Dp  = dir ? DB  : DF;
    float* y        = dir ? yB  : yF;
    const float Ac = -__expf(ldw(Al, ao + (size_t)d * 16 + n, bf));
    const float Dv = ldw(Dp, dofs + d, bf);
    float h = 0.f;
    const size_t rb = (size_t)b * 800;

    for (int s0 = 0; s0 < 800; s0 += 8) {
        float dtv[8], uv[8], Bv[8], Cv[8], zv[8];
        size_t rows[8];
        #pragma unroll
        for (int j = 0; j < 8; j++) {
            int t = dir ? 799 - (s0 + j) : (s0 + j);
            rows[j] = rb + t;
            dtv[j] = dt[rows[j] * 1024 + d];
            uv[j]  = u[rows[j] * 1024 + d];
            Bv[j]  = pr[rows[j] * 64 + 32 + n];
            Cv[j]  = pr[rows[j] * 64 + 48 + n];
            zv[j]  = z[rows[j] * 2048 + d];
        }
        #pragma unroll
        for (int j = 0; j < 8; j++) {
            h = __expf(dtv[j] * Ac) * h + (dtv[j] * uv[j]) * Bv[j];
            float c = h * Cv[j];
            c += __shfl_xor(c, 8, 16);
            c += __shfl_xor(c, 4, 16);
            c += __shfl_xor(c, 2, 16);
            c += __shfl_xor(c, 1, 16);
            if (n == 0) {
                y[rows[j] * 1024 + d] =
                    (c + uv[j] * Dv) * (zv[j] / (1.f + __expf(-zv[j])));
            }
        }
    }
}

// ---------------- LayerNorm(Y)*g+b + XT -> XT (optional fp32 emit) ---------
__global__ __launch_bounds__(256) void ln_residual(
    const float* __restrict__ Y, const void* __restrict__ g, size_t go,
    const void* __restrict__ bb, size_t bo,
    float* __restrict__ XT, float* __restrict__ out,
    const void* __restrict__ sniff)
{
    const int bf = detect_bf(sniff);
    int wv = threadIdx.x >> 6, lane = threadIdx.x & 63;
    int token = blockIdx.x * 4 + wv;
    const float* y = Y + (size_t)token * 512;
    float v[8], s = 0.f, s2 = 0.f;
    #pragma unroll
    for (int j = 0; j < 8; j++) {
        v[j] = y[lane + j * 64];
        s += v[j]; s2 += v[j] * v[j];
    }
    #pragma unroll
    for (int off = 32; off >= 1; off >>= 1) {
        s  += __shfl_xor(s,  off, 64);
        s2 += __shfl_xor(s2, off, 64);
    }
    float mean = s * (1.f / 512.f);
    float var  = s2 * (1.f / 512.f) - mean * mean;
    float rs = rsqrtf(var + 1e-5f);
    float* xt = XT + (size_t)token * 512;
    #pragma unroll
    for (int j = 0; j < 8; j++) {
        int c = lane + j * 64;
        float val = (v[j] - mean) * rs * ldw(g, go + c, bf)
                  + ldw(bb, bo + c, bf) + xt[c];
        xt[c] = val;
        if (out) out[(size_t)token * 512 + c] = val;
    }
}

// ---------------------------------------------------------------------------
extern "C" void kernel_launch(void* const* d_in, const int* in_sizes, int n_in,
                              void* d_out, int out_size, void* d_ws, size_t ws_size,
                              hipStream_t stream)
{
    (void)in_sizes; (void)n_in; (void)out_size;
    const void* X      = d_in[0];
    const void* patchW = d_in[1];
    const void* patchB = d_in[2];
    const void* inW    = d_in[3];
    const void* convW  = d_in[4];
    const void* convBi = d_in[5];
    const void* xprojW = d_in[6];
    const void* dtW    = d_in[7];
    const void* dtBias = d_in[8];
    const void* Alog   = d_in[9];
    const void* Dsk    = d_in[10];
    const void* convWb = d_in[11];
    const void* convBb = d_in[12];
    const void* xprojWb= d_in[13];
    const void* dtWb   = d_in[14];
    const void* dtBiasb= d_in[15];
    const void* Alogb  = d_in[16];
    const void* Dskb   = d_in[17];
    const void* outW   = d_in[18];
    const void* ln1g   = d_in[19];
    const void* ln1b   = d_in[20];
    const void* fc1W   = d_in[21];
    const void* fc1B   = d_in[22];
    const void* fc2W   = d_in[23];
    const void* fc2B   = d_in[24];
    const void* ln2g   = d_in[25];
    const void* ln2b   = d_in[26];
    const void* SN     = patchW;            // dtype sniff target

    // chunking: per-chunk need = Mc * 6784 floats
    int nc = 1;
    if ((size_t)6400 * 6784 * 4 > ws_size) nc = 2;
    if ((size_t)3200 * 6784 * 4 > ws_size) nc = 4;
    if ((size_t)1600 * 6784 * 4 > ws_size) nc = 8;
    const int bc = 8 / nc;
    const int Mc = bc * 800;
    const int GY = Mc / 64;

    float* ws   = (float*)d_ws;
    float* XT   = ws;                           // Mc*512  (residual stream)
    float* XZ   = XT  + (size_t)Mc * 512;       // Mc*2048 (xm | z)
    float* XCF  = XZ  + (size_t)Mc * 2048;      // Mc*1024 (patch-A, convF, yF)
    float* XCB  = XCF + (size_t)Mc * 1024;      // Mc*1024 (convB, yB)
    float* PRF  = XCB + (size_t)Mc * 1024;      // Mc*64
    float* PRB  = PRF + (size_t)Mc * 64;        // Mc*64
    float* DTF  = PRB + (size_t)Mc * 64;        // Mc*1024
    float* DTB  = DTF + (size_t)Mc * 1024;      // Mc*1024
    float* PATCH = XCF;
    float* M1   = XZ;                           // MLP hidden (XZ dead post-scan)
    float* YO   = XZ + (size_t)Mc * 1024;       // out_proj out / MLP out
    float* M2   = YO;

    for (int c = 0; c < nc; c++) {
        const size_t x0 = (size_t)c * bc * 819200;

        im2col_patch<<<Mc, 256, 0, stream>>>(X, x0, PATCH, SN);
        gemm_f32<1, false><<<dim3(8, GY), 256, 0, stream>>>(
            PATCH, nullptr, patchW, 0, patchB, 0, XT,
            512, 1024, 1024, 512, 512, SN);

        for (int l = 0; l < 8; l++) {
            // in_proj: (Mc x 512) @ (512 x 2048) -> XZ (xm | z)
            gemm_f32<0, false><<<dim3(32, GY), 256, 0, stream>>>(
                XT, nullptr, inW, (size_t)l * 1048576, nullptr, 0, XZ,
                2048, 512, 512, 2048, 2048, SN);
            // depthwise conv both dirs + SiLU
            conv_dual<<<Mc * 4, 256, 0, stream>>>(
                XZ, convW, (size_t)l * 4096, convBi, (size_t)l * 1024,
                convWb, (size_t)l * 4096, convBb, (size_t)l * 1024,
                XCF, XCB, SN);
            // x-proj both dirs (fused dispatch): (Mc x 1024) @ (1024 x 64)
            gemm_dual<0><<<dim3(1, GY, 2), 256, 0, stream>>>(
                XCF, XCB, xprojW, (size_t)l * 65536, xprojWb, (size_t)l * 65536,
                nullptr, 0, nullptr, 0, PRF, PRB,
                64, 1024, 1024, 64, 64, SN);
            // dt both dirs (fused): softplus((Mc x 32) @ (32 x 1024) + bias)
            gemm_dual<2><<<dim3(16, GY, 2), 256, 0, stream>>>(
                PRF, PRB, dtW, (size_t)l * 32768, dtWb, (size_t)l * 32768,
                dtBias, (size_t)l * 1024, dtBiasb, (size_t)l * 1024,
                DTF, DTB, 1024, 32, 64, 1024, 1024, SN);
            // selective scan both dirs (in-place y over u)
            ssm_scan<<<dim3(64, bc, 2), 256, 0, stream>>>(
                XCF, DTF, PRF, XCB, DTB, PRB,
                Alog, Alogb, (size_t)l * 16384,
                Dsk, Dskb, (size_t)l * 1024,
                XZ + 1024, XCF, XCB, SN);
            // out_proj with fused (yF + yB): (Mc x 1024) @ (1024 x 512)
            gemm_f32<0, true><<<dim3(8, GY), 256, 0, stream>>>(
                XCF, XCB, outW, (size_t)l * 524288, nullptr, 0, YO,
                512, 1024, 1024, 512, 512, SN);
            ln_residual<<<Mc / 4, 256, 0, stream>>>(
                YO, ln1g, (size_t)l * 512, ln1b, (size_t)l * 512, XT,
                nullptr, SN);
            // MLP
            gemm_f32<3, false><<<dim3(16, GY), 256, 0, stream>>>(
                XT, nullptr, fc1W, (size_t)l * 524288, fc1B, (size_t)l * 1024,
                M1, 1024, 512, 512, 1024, 1024, SN);
            gemm_f32<1, false><<<dim3(8, GY), 256, 0, stream>>>(
                M1, nullptr, fc2W, (size_t)l * 524288, fc2B, (size_t)l * 512,
                M2, 512, 1024, 1024, 512, 512, SN);
            ln_residual<<<Mc / 4, 256, 0, stream>>>(
                M2, ln2g, (size_t)l * 512, ln2b, (size_t)l * 512, XT,
                (float*)d_out + (size_t)l * 3276800 + (size_t)c * Mc * 512, SN);
        }
    }
}

// Round 7
// 4953.735 us; speedup vs baseline: 2.3462x; 1.6001x over previous
//
#include <hip/hip_runtime.h>

// ---------------------------------------------------------------------------
// MambaEncoder on MI355X — round 7: big GEMMs -> bf16 MFMA (16x16x32),
// one-time weight transpose-convert to [N][K] bf16, bf16 activation shadows.
// Scan/conv/xproj/dt unchanged fp32. fp32 output.
// Dims: NL=8, DM=512, DI=1024, DS=16, DC=4, DR=32, B=8, L=800.
// ---------------------------------------------------------------------------

typedef unsigned short u16;
typedef unsigned long long u64;
typedef short s16x8 __attribute__((ext_vector_type(8)));   // 8 bf16 (4 VGPR)
typedef float f32x4 __attribute__((ext_vector_type(4)));   // 4 fp32 acc

__device__ __forceinline__ float b2f(u16 u) {
    return __uint_as_float(((unsigned)u) << 16);
}
__device__ __forceinline__ u16 f2b(float f) {
    unsigned u = __float_as_uint(f);
    return (u16)((u + 0x7fffu + ((u >> 16) & 1u)) >> 16);   // RNE
}
__device__ __forceinline__ float ldw(const void* p, size_t i, int bf) {
    return bf ? b2f(((const u16*)p)[i]) : ((const float*)p)[i];
}
__device__ __forceinline__ float4 ldw4(const void* p, size_t i, int bf) {
    if (bf) {
        ushort4 v = *(const ushort4*)((const u16*)p + i);
        return make_float4(b2f(v.x), b2f(v.y), b2f(v.z), b2f(v.w));
    }
    return *(const float4*)((const float*)p + i);
}

// Per-wave dtype sniff of patch_w (values ~N(0,0.02)): bf16 storage -> all 64
// sampled u16s have sane exponents; fp32 storage -> only high halves (~36/64).
__device__ __forceinline__ int detect_bf(const void* w) {
    const u16* p = (const u16*)w;
    unsigned e = (p[threadIdx.x & 63] >> 7) & 0xFFu;
    u64 m = __ballot((e >= 0x60u) && (e <= 0x7Fu));
    return __popcll(m) >= 50 ? 1 : 0;
}

// EPI: 0 none(no bias), 1 +bias, 2 +bias softplus, 3 +bias gelu(erf)
template<int EPI>
__device__ __forceinline__ float epi_act(float x) {
    if (EPI == 2) return x > 20.f ? x : log1pf(__expf(x));
    if (EPI == 3) return 0.5f * x * (1.f + erff(x * 0.7071067811865476f));
    return x;
}

// ---------------- one-time weight transpose-convert: W[K][N] -> WT[N][K] bf16
// block (32,8); grid (N/32, K/32, layers); LDS-tiled, both sides coalesced.
__global__ __launch_bounds__(256) void transp_cvt(
    const void* __restrict__ src, u16* __restrict__ dst, int K, int N,
    const void* __restrict__ sniff)
{
    const int bf = detect_bf(sniff);
    __shared__ u16 tile[32][33];
    const int n0 = blockIdx.x * 32, k0 = blockIdx.y * 32;
    const size_t loff = (size_t)blockIdx.z * K * N;
    const int tx = threadIdx.x, ty = threadIdx.y;
    #pragma unroll
    for (int r = 0; r < 4; r++) {
        int ky = ty + r * 8;
        tile[ky][tx] = f2b(ldw(src, loff + (size_t)(k0 + ky) * N + n0 + tx, bf));
    }
    __syncthreads();
    #pragma unroll
    for (int r = 0; r < 4; r++) {
        int ny = ty + r * 8;
        dst[loff + (size_t)(n0 + ny) * K + k0 + tx] = tile[tx][ny];
    }
}

// ---------------- bf16 MFMA GEMM: C = act(A @ W (+bias)) -------------------
// A bf16 MxK row-major; WT bf16 [N][K] at element offset woff. BM=BN=128,
// BK=32, 256 thr = 4 waves x (4x4 of 16x16x32). XOR-swizzled LDS chunks
// (s=(row>>1)&3) -> 2-way-conflict ds_read_b128 (free, m136).
template<int EPI, bool OUTF, bool OUTB>
__global__ __launch_bounds__(256) void gemm_mfma(
    const u16* __restrict__ A, const u16* __restrict__ WT, size_t woff,
    const void* __restrict__ bias, size_t soff,
    float* __restrict__ Cf, u16* __restrict__ Cb,
    int M, int N, int K, const void* __restrict__ sniff)
{
    const int bf = detect_bf(sniff);
    __shared__ __align__(16) u16 As[128 * 32];
    __shared__ __align__(16) u16 Bs[128 * 32];
    const int tid = threadIdx.x;
    const int bm = blockIdx.y * 128, bn = blockIdx.x * 128;
    const int w = tid >> 6, lane = tid & 63;
    const int wm = (w >> 1) * 64, wn = (w & 1) * 64;
    const int lrow = lane & 15, q = lane >> 4;
    const u16* Wp = WT + woff;

    f32x4 acc[4][4];
    const f32x4 z4 = {0.f, 0.f, 0.f, 0.f};
    #pragma unroll
    for (int i = 0; i < 4; i++)
        #pragma unroll
        for (int j = 0; j < 4; j++) acc[i][j] = z4;

    for (int k0 = 0; k0 < K; k0 += 32) {
        if (k0) __syncthreads();
        #pragma unroll
        for (int c = 0; c < 2; c++) {
            int jj = tid + c * 256;            // 512 chunks of 16B per tile
            int r = jj >> 2, kc = jj & 3;
            int kg = kc ^ ((r >> 1) & 3);      // swizzled source chunk
            int ra = bm + r; if (ra >= M) ra = M - 1;
            *(s16x8*)(As + r * 32 + kc * 8) =
                *(const s16x8*)(A + (size_t)ra * K + k0 + kg * 8);
            *(s16x8*)(Bs + r * 32 + kc * 8) =
                *(const s16x8*)(Wp + (size_t)(bn + r) * K + k0 + kg * 8);
        }
        __syncthreads();
        s16x8 af[4], bfr[4];
        #pragma unroll
        for (int mt = 0; mt < 4; mt++) {
            int m_ = wm + mt * 16 + lrow;
            af[mt] = *(const s16x8*)(As + m_ * 32 + ((q ^ ((m_ >> 1) & 3)) << 3));
        }
        #pragma unroll
        for (int nt = 0; nt < 4; nt++) {
            int n_ = wn + nt * 16 + lrow;
            bfr[nt] = *(const s16x8*)(Bs + n_ * 32 + ((q ^ ((n_ >> 1) & 3)) << 3));
        }
        #pragma unroll
        for (int mt = 0; mt < 4; mt++)
            #pragma unroll
            for (int nt = 0; nt < 4; nt++)
                acc[mt][nt] = __builtin_amdgcn_mfma_f32_16x16x32_bf16(
                    af[mt], bfr[nt], acc[mt][nt], 0, 0, 0);
    }

    float bv[4] = {0.f, 0.f, 0.f, 0.f};
    if (EPI >= 1) {
        #pragma unroll
        for (int nt = 0; nt < 4; nt++)
            bv[nt] = ldw(bias, soff + (size_t)(bn + wn + nt * 16 + lrow), bf);
    }
    #pragma unroll
    for (int mt = 0; mt < 4; mt++) {
        #pragma unroll
        for (int nt = 0; nt < 4; nt++) {
            int n = bn + wn + nt * 16 + lrow;
            #pragma unroll
            for (int reg = 0; reg < 4; reg++) {
                int m = bm + wm + mt * 16 + q * 4 + reg;
                if (m < M) {
                    float v = epi_act<EPI>(acc[mt][nt][reg] + bv[nt]);
                    if (OUTF) Cf[(size_t)m * N + n] = v;
                    if (OUTB) Cb[(size_t)m * N + n] = f2b(v);
                }
            }
        }
    }
}

// ---------------- fp32 GEMM body (kept for xproj/dt; A fp32 internal) ------
template<int EPI>
__device__ __forceinline__ void gemm_body(
    const float* __restrict__ A,
    const void* __restrict__ Bw, size_t boff,
    const void* __restrict__ bias, size_t soff,
    float* __restrict__ C, int N, int K, int lda, int ldb, int ldc, int bf)
{
    __shared__ float As[16][68];
    __shared__ float Bs[16][68];
    const int tid = threadIdx.x;
    const int bm = blockIdx.y * 64;
    const int bn = blockIdx.x * 64;
    const int arow = tid >> 2, acol = (tid & 3) << 2;
    const int brow = tid >> 4, bcol = (tid & 15) << 2;
    const int ty = tid >> 4, tx = tid & 15;
    float acc[4][4] = {};

    const float* aptr = A + (size_t)(bm + arow) * lda + acol;
    const size_t bidx0 = boff + (size_t)brow * ldb + bn + bcol;

    for (int k0 = 0; k0 < K; k0 += 16) {
        float4 av = *(const float4*)(aptr + k0);
        float4 bvv = ldw4(Bw, bidx0 + (size_t)k0 * ldb, bf);
        As[acol + 0][arow] = av.x;
        As[acol + 1][arow] = av.y;
        As[acol + 2][arow] = av.z;
        As[acol + 3][arow] = av.w;
        Bs[brow][bcol + 0] = bvv.x;
        Bs[brow][bcol + 1] = bvv.y;
        Bs[brow][bcol + 2] = bvv.z;
        Bs[brow][bcol + 3] = bvv.w;
        __syncthreads();
        #pragma unroll
        for (int kk = 0; kk < 16; kk++) {
            float4 a4 = *(const float4*)&As[kk][ty << 2];
            float4 b4 = *(const float4*)&Bs[kk][tx << 2];
            float ar[4] = {a4.x, a4.y, a4.z, a4.w};
            float br[4] = {b4.x, b4.y, b4.z, b4.w};
            #pragma unroll
            for (int i = 0; i < 4; i++)
                #pragma unroll
                for (int j = 0; j < 4; j++)
                    acc[i][j] = fmaf(ar[i], br[j], acc[i][j]);
        }
        __syncthreads();
    }

    float bv4[4] = {0.f, 0.f, 0.f, 0.f};
    if (EPI >= 1) {
        float4 bb = ldw4(bias, soff + (size_t)(bn + (tx << 2)), bf);
        bv4[0] = bb.x; bv4[1] = bb.y; bv4[2] = bb.z; bv4[3] = bb.w;
    }
    #pragma unroll
    for (int i = 0; i < 4; i++) {
        float4 o;
        o.x = epi_act<EPI>(acc[i][0] + bv4[0]);
        o.y = epi_act<EPI>(acc[i][1] + bv4[1]);
        o.z = epi_act<EPI>(acc[i][2] + bv4[2]);
        o.w = epi_act<EPI>(acc[i][3] + bv4[3]);
        *(float4*)(C + (size_t)(bm + (ty << 2) + i) * ldc + bn + (tx << 2)) = o;
    }
}

// Dual-direction fp32 GEMM: blockIdx.z selects (A,Bw,bias,C) set.
template<int EPI>
__global__ __launch_bounds__(256) void gemm_dual(
    const float* __restrict__ A0, const float* __restrict__ A1,
    const void* __restrict__ Bw0, size_t boff0,
    const void* __restrict__ Bw1, size_t boff1,
    const void* __restrict__ bias0, size_t sof0,
    const void* __restrict__ bias1, size_t sof1,
    float* __restrict__ C0, float* __restrict__ C1,
    int N, int K, int lda, int ldb, int ldc,
    const void* __restrict__ sniff)
{
    const int bf = detect_bf(sniff);
    if (blockIdx.z == 0)
        gemm_body<EPI>(A0, Bw0, boff0, bias0, sof0, C0, N, K, lda, ldb, ldc, bf);
    else
        gemm_body<EPI>(A1, Bw1, boff1, bias1, sof1, C1, N, K, lda, ldb, ldc, bf);
}

// ---------------- patch gather (im2col) -> bf16 A ---------------------------
__global__ __launch_bounds__(256) void im2col_patch(
    const void* __restrict__ x, size_t x0, u16* __restrict__ Pb,
    const void* __restrict__ sniff)
{
    const int bf = detect_bf(sniff);
    int idx = blockIdx.x * 256 + threadIdx.x;
    int p2 = idx & 15; int r = idx >> 4;
    int p1 = r & 15;  r >>= 4;
    int w = r % 10;   r /= 10;
    int h = r % 10;   r /= 10;
    int f = r & 7;    int b = r >> 3;
    int token = f * 100 + h * 10 + w;
    size_t xb = x0 + ((size_t)(b * 32 + f * 4) * 160 + h * 16 + p1) * 160
                   + (w * 16 + p2);
    ushort4 o;
    o.x = f2b(ldw(x, xb,         bf));
    o.y = f2b(ldw(x, xb + 25600, bf));
    o.z = f2b(ldw(x, xb + 51200, bf));
    o.w = f2b(ldw(x, xb + 76800, bf));
    *(ushort4*)(Pb + (size_t)(b * 800 + token) * 1024 + ((p1 * 16 + p2) << 2)) = o;
}

// ---------------- dual depthwise conv + SiLU (fp32) ------------------------
__global__ __launch_bounds__(256) void conv_dual(
    const float* __restrict__ xm,
    const void* __restrict__ cwF, size_t wFo,
    const void* __restrict__ cbF, size_t bFo,
    const void* __restrict__ cwB, size_t wBo,
    const void* __restrict__ cbB, size_t bBo,
    float* __restrict__ xcf, float* __restrict__ xcb,
    const void* __restrict__ sniff)
{
    const int bf = detect_bf(sniff);
    int idx = blockIdx.x * 256 + threadIdx.x;
    int d = idx & 1023;
    int bt = idx >> 10;
    int t = bt % 800, b = bt / 800;
    const float* base = xm + (size_t)b * 800 * 2048 + d;
    float v[7];
    #pragma unroll
    for (int j = 0; j < 7; j++) {
        int tt = t + j - 3;
        v[j] = (tt >= 0 && tt < 800) ? base[(size_t)tt * 2048] : 0.f;
    }
    float4 wf = ldw4(cwF, wFo + (size_t)d * 4, bf);
    float4 wb = ldw4(cwB, wBo + (size_t)d * 4, bf);
    float f = ldw(cbF, bFo + d, bf) + wf.x * v[0] + wf.y * v[1]
                                    + wf.z * v[2] + wf.w * v[3];
    float g = ldw(cbB, bBo + d, bf) + wb.x * v[6] + wb.y * v[5]
                                    + wb.z * v[4] + wb.w * v[3];
    xcf[(size_t)bt * 1024 + d] = f / (1.f + __expf(-f));
    xcb[(size_t)bt * 1024 + d] = g / (1.f + __expf(-g));
}

// ---------------- selective scan (unchanged from round 6) ------------------
__global__ __launch_bounds__(256) void ssm_scan(
    const float* uF, const float* dtF, const float* __restrict__ pF,
    const float* uB, const float* dtB, const float* __restrict__ pB,
    const void* __restrict__ AlF, const void* __restrict__ AlB, size_t ao,
    const void* __restrict__ DF,  const void* __restrict__ DB,  size_t dofs,
    const float* __restrict__ z,
    float* yF, float* yB, const void* __restrict__ sniff)
{
    const int bf = detect_bf(sniff);
    const int dir = blockIdx.z;
    const int b = blockIdx.y;
    const int tid = threadIdx.x;
    const int dl = tid >> 4, n = tid & 15;
    const int d = blockIdx.x * 16 + dl;
    const float* u  = dir ? uB  : uF;
    const float* dt = dir ? dtB : dtF;
    const float* pr = dir ? pB  : pF;
    const void* Al  = dir ? AlB : AlF;
    const void* Dp  = dir ? DB  : DF;
    float* y        = dir ? yB  : yF;
    const float Ac = -__expf(ldw(Al, ao + (size_t)d * 16 + n, bf));
    const float Dv = ldw(Dp, dofs + d, bf);
    float h = 0.f;
    const size_t rb = (size_t)b * 800;

    for (int s0 = 0; s0 < 800; s0 += 8) {
        float dtv[8], uv[8], Bv[8], Cv[8], zv[8];
        size_t rows[8];
        #pragma unroll
        for (int j = 0; j < 8; j++) {
            int t = dir ? 799 - (s0 + j) : (s0 + j);
            rows[j] = rb + t;
            dtv[j] = dt[rows[j] * 1024 + d];
            uv[j]  = u[rows[j] * 1024 + d];
            Bv[j]  = pr[rows[j] * 64 + 32 + n];
            Cv[j]  = pr[rows[j] * 64 + 48 + n];
            zv[j]  = z[rows[j] * 2048 + d];
        }
        #pragma unroll
        for (int j = 0; j < 8; j++) {
            h = __expf(dtv[j] * Ac) * h + (dtv[j] * uv[j]) * Bv[j];
            float c = h * Cv[j];
            c += __shfl_xor(c, 8, 16);
            c += __shfl_xor(c, 4, 16);
            c += __shfl_xor(c, 2, 16);
            c += __shfl_xor(c, 1, 16);
            if (n == 0) {
                y[rows[j] * 1024 + d] =
                    (c + uv[j] * Dv) * (zv[j] / (1.f + __expf(-zv[j])));
            }
        }
    }
}

// ---------------- yF+yB -> bf16 (out_proj A) -------------------------------
__global__ __launch_bounds__(256) void addcvt(
    const float* __restrict__ a, const float* __restrict__ b,
    u16* __restrict__ o)
{
    int i = (blockIdx.x * 256 + threadIdx.x) * 4;
    float4 va = *(const float4*)(a + i);
    float4 vb = *(const float4*)(b + i);
    ushort4 r;
    r.x = f2b(va.x + vb.x); r.y = f2b(va.y + vb.y);
    r.z = f2b(va.z + vb.z); r.w = f2b(va.w + vb.w);
    *(ushort4*)(o + i) = r;
}

// ---------------- LayerNorm + residual -> XT fp32 + XTb bf16 (+fp32 out) ---
__global__ __launch_bounds__(256) void ln_residual(
    const float* __restrict__ Y, const void* __restrict__ g, size_t go,
    const void* __restrict__ bb, size_t bo,
    float* __restrict__ XT, u16* __restrict__ XTb, float* __restrict__ out,
    const void* __restrict__ sniff)
{
    const int bf = detect_bf(sniff);
    int wv = threadIdx.x >> 6, lane = threadIdx.x & 63;
    int token = blockIdx.x * 4 + wv;
    const float* y = Y + (size_t)token * 512;
    float v[8], s = 0.f, s2 = 0.f;
    #pragma unroll
    for (int j = 0; j < 8; j++) {
        v[j] = y[lane + j * 64];
        s += v[j]; s2 += v[j] * v[j];
    }
    #pragma unroll
    for (int off = 32; off >= 1; off >>= 1) {
        s  += __shfl_xor(s,  off, 64);
        s2 += __shfl_xor(s2, off, 64);
    }
    float mean = s * (1.f / 512.f);
    float var  = s2 * (1.f / 512.f) - mean * mean;
    float rs = rsqrtf(var + 1e-5f);
    float* xt = XT + (size_t)token * 512;
    #pragma unroll
    for (int j = 0; j < 8; j++) {
        int c = lane + j * 64;
        float val = (v[j] - mean) * rs * ldw(g, go + c, bf)
                  + ldw(bb, bo + c, bf) + xt[c];
        xt[c] = val;
        XTb[(size_t)token * 512 + c] = f2b(val);
        if (out) out[(size_t)token * 512 + c] = val;
    }
}

// ---------------------------------------------------------------------------
extern "C" void kernel_launch(void* const* d_in, const int* in_sizes, int n_in,
                              void* d_out, int out_size, void* d_ws, size_t ws_size,
                              hipStream_t stream)
{
    (void)in_sizes; (void)n_in; (void)out_size;
    const void* X      = d_in[0];
    const void* patchW = d_in[1];
    const void* patchB = d_in[2];
    const void* inW    = d_in[3];
    const void* convW  = d_in[4];
    const void* convBi = d_in[5];
    const void* xprojW = d_in[6];
    const void* dtW    = d_in[7];
    const void* dtBias = d_in[8];
    const void* Alog   = d_in[9];
    const void* Dsk    = d_in[10];
    const void* convWb = d_in[11];
    const void* convBb = d_in[12];
    const void* xprojWb= d_in[13];
    const void* dtWb   = d_in[14];
    const void* dtBiasb= d_in[15];
    const void* Alogb  = d_in[16];
    const void* Dskb   = d_in[17];
    const void* outW   = d_in[18];
    const void* ln1g   = d_in[19];
    const void* ln1b   = d_in[20];
    const void* fc1W   = d_in[21];
    const void* fc1B   = d_in[22];
    const void* fc2W   = d_in[23];
    const void* fc2B   = d_in[24];
    const void* ln2g   = d_in[25];
    const void* ln2b   = d_in[26];
    const void* SN     = patchW;            // dtype sniff target

    // bf16 weight arena (u16 offsets)
    const size_t IN_OFF  = 524288;          // after patchWT
    const size_t OUT_OFF = 8912896;
    const size_t FC1_OFF = 13107200;
    const size_t FC2_OFF = 17301504;
    const size_t WB_FLOATS = 10747904;      // 21495808 u16 / 2

    // chunking: bytes = (WB + Mc*8064 + pad)*4
    int nc = 1;
    auto need = [&](int Mc) {
        return (WB_FLOATS + (size_t)Mc * 8064 + 16384) * 4;
    };
    if (need(6400) > ws_size) nc = 2;
    if (need(3200) > ws_size) nc = 4;
    const int bc = 8 / nc;
    const int Mc = bc * 800;
    const int GY = Mc / 64;                 // fp32-GEMM grid
    const int GYM = (Mc + 127) / 128;       // MFMA grid

    u16* WB = (u16*)d_ws;
    float* cur = (float*)d_ws + WB_FLOATS;
    float* XT  = cur;              cur += (size_t)Mc * 512;
    u16*  XTb  = (u16*)cur;        cur += (size_t)Mc * 256;
    float* XZ  = cur;              cur += (size_t)Mc * 2048;
    float* XCF = cur;              cur += (size_t)Mc * 1024;
    float* XCB = cur;              cur += (size_t)Mc * 1024;
    float* PRF = cur;              cur += (size_t)Mc * 64;
    float* PRB = cur;              cur += (size_t)Mc * 64;
    float* DTF = cur;              cur += (size_t)Mc * 1024;
    float* DTB = cur;              cur += (size_t)Mc * 1024;
    u16*  M1b  = (u16*)cur;        cur += (size_t)Mc * 512;
    u16*  YSb  = (u16*)cur;        cur += (size_t)Mc * 512;
    u16*  PATCHb = (u16*)XCF;               // alias (dead before conv)
    float* YO  = XZ;                        // alias (XZ dead post-scan)
    float* M2  = XZ + (size_t)Mc * 512;     // alias, disjoint from YO

    // ---- one-time weight transpose-convert to bf16 [N][K] -----------------
    transp_cvt<<<dim3(16, 32, 1), dim3(32, 8), 0, stream>>>(patchW, WB, 1024, 512, SN);
    transp_cvt<<<dim3(64, 16, 8), dim3(32, 8), 0, stream>>>(inW,  WB + IN_OFF, 512, 2048, SN);
    transp_cvt<<<dim3(16, 32, 8), dim3(32, 8), 0, stream>>>(outW, WB + OUT_OFF, 1024, 512, SN);
    transp_cvt<<<dim3(32, 16, 8), dim3(32, 8), 0, stream>>>(fc1W, WB + FC1_OFF, 512, 1024, SN);
    transp_cvt<<<dim3(16, 32, 8), dim3(32, 8), 0, stream>>>(fc2W, WB + FC2_OFF, 1024, 512, SN);

    for (int c = 0; c < nc; c++) {
        const size_t x0 = (size_t)c * bc * 819200;

        im2col_patch<<<Mc, 256, 0, stream>>>(X, x0, PATCHb, SN);
        // patch embed: (Mc x 1024) @ (1024 x 512) + bias -> XT fp32 + XTb bf16
        gemm_mfma<1, true, true><<<dim3(4, GYM), 256, 0, stream>>>(
            PATCHb, WB, 0, patchB, 0, XT, XTb, Mc, 512, 1024, SN);

        for (int l = 0; l < 8; l++) {
            // in_proj: (Mc x 512) @ (512 x 2048) -> XZ fp32
            gemm_mfma<0, true, false><<<dim3(16, GYM), 256, 0, stream>>>(
                XTb, WB, IN_OFF + (size_t)l * 1048576, nullptr, 0,
                XZ, nullptr, Mc, 2048, 512, SN);
            // depthwise conv both dirs + SiLU
            conv_dual<<<Mc * 4, 256, 0, stream>>>(
                XZ, convW, (size_t)l * 4096, convBi, (size_t)l * 1024,
                convWb, (size_t)l * 4096, convBb, (size_t)l * 1024,
                XCF, XCB, SN);
            // x-proj both dirs (fp32): (Mc x 1024) @ (1024 x 64)
            gemm_dual<0><<<dim3(1, GY, 2), 256, 0, stream>>>(
                XCF, XCB, xprojW, (size_t)l * 65536, xprojWb, (size_t)l * 65536,
                nullptr, 0, nullptr, 0, PRF, PRB,
                64, 1024, 1024, 64, 64, SN);
            // dt both dirs (fp32): softplus((Mc x 32) @ (32 x 1024) + bias)
            gemm_dual<2><<<dim3(16, GY, 2), 256, 0, stream>>>(
                PRF, PRB, dtW, (size_t)l * 32768, dtWb, (size_t)l * 32768,
                dtBias, (size_t)l * 1024, dtBiasb, (size_t)l * 1024,
                DTF, DTB, 1024, 32, 64, 1024, 1024, SN);
            // selective scan both dirs (in-place y over u)
            ssm_scan<<<dim3(64, bc, 2), 256, 0, stream>>>(
                XCF, DTF, PRF, XCB, DTB, PRB,
                Alog, Alogb, (size_t)l * 16384,
                Dsk, Dskb, (size_t)l * 1024,
                XZ + 1024, XCF, XCB, SN);
            // yF + yB -> bf16
            addcvt<<<Mc, 256, 0, stream>>>(XCF, XCB, YSb);
            // out_proj: (Mc x 1024) @ (1024 x 512) -> YO fp32
            gemm_mfma<0, true, false><<<dim3(4, GYM), 256, 0, stream>>>(
                YSb, WB, OUT_OFF + (size_t)l * 524288, nullptr, 0,
                YO, nullptr, Mc, 512, 1024, SN);
            ln_residual<<<Mc / 4, 256, 0, stream>>>(
                YO, ln1g, (size_t)l * 512, ln1b, (size_t)l * 512,
                XT, XTb, nullptr, SN);
            // fc1: (Mc x 512) @ (512 x 1024) + bias, gelu -> M1b bf16
            gemm_mfma<3, false, true><<<dim3(8, GYM), 256, 0, stream>>>(
                XTb, WB, FC1_OFF + (size_t)l * 524288, fc1B, (size_t)l * 1024,
                nullptr, M1b, Mc, 1024, 512, SN);
            // fc2: (Mc x 1024) @ (1024 x 512) + bias -> M2 fp32
            gemm_mfma<1, true, false><<<dim3(4, GYM), 256, 0, stream>>>(
                M1b, WB, FC2_OFF + (size_t)l * 524288, fc2B, (size_t)l * 512,
                M2, nullptr, Mc, 512, 1024, SN);
            ln_residual<<<Mc / 4, 256, 0, stream>>>(
                M2, ln2g, (size_t)l * 512, ln2b, (size_t)l * 512,
                XT, XTb,
                (float*)d_out + (size_t)l * 3276800 + (size_t)c * Mc * 512, SN);
        }
    }
}